// Round 2
// baseline (704.354 us; speedup 1.0000x reference)
//
#include <hip/hip_runtime.h>

#define BS 512
#define SRC 36
#define H 1024
#define MID 4096
#define M_ROWS (BS * SRC)   // 18432
#define ALPHAF 8.0f
#define GAMMAF 0.98f
#define EPSF 1e-6f

typedef __bf16 bf16;
typedef __attribute__((ext_vector_type(8))) __bf16 bf16x8;
typedef __attribute__((ext_vector_type(4))) __bf16 bf16x4;
typedef __attribute__((ext_vector_type(4))) float f32x4;
typedef __attribute__((ext_vector_type(4))) int i32x4;

// ---------------- helpers ----------------
__device__ __forceinline__ float wave_reduce_sum(float v) {
    #pragma unroll
    for (int off = 32; off > 0; off >>= 1) v += __shfl_xor(v, off, 64);
    return v;
}

// ---------------- sum(ru) ----------------
__global__ __launch_bounds__(256) void k_rusum(const float* __restrict__ ru,
                                               float* __restrict__ rusum) {
    int i = blockIdx.x * 256 + threadIdx.x;
    float v = ru[i];
    v = wave_reduce_sum(v);
    __shared__ float s[4];
    if ((threadIdx.x & 63) == 0) s[threadIdx.x >> 6] = v;
    __syncthreads();
    if (threadIdx.x == 0) atomicAdd(rusum, s[0] + s[1] + s[2] + s[3]);
}

// ---------------- gate: rg, ru_new, focal_att, ru_out, w ----------------
__global__ __launch_bounds__(64) void k_gate(const float* __restrict__ att,
                                             const float* __restrict__ ru,
                                             const float* __restrict__ rusum,
                                             float* __restrict__ w,
                                             float* __restrict__ ru_out) {
    int b = blockIdx.x;
    int s = threadIdx.x;   // 64 threads, 36 active
    float rg = 0.f, run = 0.f;
    if (s < SRC) {
        const float* row = att + ((size_t)b * SRC + s) * SRC;
        #pragma unroll
        for (int j = 0; j < SRC; ++j) rg += row[j];
        float scale = (*rusum == 0.0f) ? 1.0f : (1.0f / (1.0f + GAMMAF));
        run = (ru[b * SRC + s] * GAMMAF + rg) * scale;
    }
    float sa = (s < SRC) ? sqrtf(run) : 0.f;
    float S = wave_reduce_sum(sa);
    float T = wave_reduce_sum(run * sa);
    if (s < SRC) {
        float funcF = run * S - T;
        float aw = (funcF > 0.f) ? ALPHAF : (1.0f / ALPHAF);
        ru_out[b * SRC + s] = aw * run;
        w[b * SRC + s] = aw * rg;
    }
}

// ---------------- transpose f32 [rows][cols] -> bf16 [cols][rows] ----------------
__global__ __launch_bounds__(256) void k_transpose_bf16(const float* __restrict__ in,
                                                        bf16* __restrict__ out,
                                                        int rows, int cols) {
    __shared__ float tile[32][33];
    int bx = blockIdx.x * 32, by = blockIdx.y * 32;
    int tx = threadIdx.x;
    #pragma unroll
    for (int j = threadIdx.y; j < 32; j += 8)
        tile[j][tx] = in[(size_t)(by + j) * cols + bx + tx];
    __syncthreads();
    #pragma unroll
    for (int j = threadIdx.y; j < 32; j += 8)
        out[(size_t)(bx + j) * rows + by + tx] = (bf16)tile[tx][j];
}

// ---------------- LN1 fused with w-scale -> mm (bf16) ----------------
__global__ __launch_bounds__(256) void k_ln1(const f32x4* __restrict__ v,
                                             const f32x4* __restrict__ q,
                                             const f32x4* __restrict__ g1,
                                             const f32x4* __restrict__ b1,
                                             const float* __restrict__ w,
                                             bf16x4* __restrict__ mm) {
    int row = blockIdx.x, t = threadIdx.x;
    size_t i = (size_t)row * 256 + t;
    f32x4 x = v[i];
    f32x4 y = q[i];
    x.x += y.x; x.y += y.y; x.z += y.z; x.w += y.w;
    float sum = x.x + x.y + x.z + x.w;
    float sq  = x.x * x.x + x.y * x.y + x.z * x.z + x.w * x.w;
    sum = wave_reduce_sum(sum);
    sq  = wave_reduce_sum(sq);
    __shared__ float ss[4], s2[4];
    if ((t & 63) == 0) { ss[t >> 6] = sum; s2[t >> 6] = sq; }
    __syncthreads();
    sum = ss[0] + ss[1] + ss[2] + ss[3];
    sq  = s2[0] + s2[1] + s2[2] + s2[3];
    float mu  = sum * (1.0f / H);
    float var = sq * (1.0f / H) - mu * mu;
    float inv = rsqrtf(var + EPSF);
    float ww = w[row];
    f32x4 g = g1[t], b = b1[t];
    bf16x4 o;
    o.x = (bf16)(ww * ((x.x - mu) * inv * g.x + b.x));
    o.y = (bf16)(ww * ((x.y - mu) * inv * g.y + b.y));
    o.z = (bf16)(ww * ((x.z - mu) * inv * g.z + b.z));
    o.w = (bf16)(ww * ((x.w - mu) * inv * g.w + b.w));
    mm[i] = o;
}

// ---------------- LN2: out = LN(mm + fc), in place over d_out ----------------
__global__ __launch_bounds__(256) void k_ln2(float* __restrict__ out,
                                             const bf16x4* __restrict__ mm,
                                             const f32x4* __restrict__ g2,
                                             const f32x4* __restrict__ b2) {
    int row = blockIdx.x, t = threadIdx.x;
    size_t i = (size_t)row * 256 + t;
    f32x4* outv = (f32x4*)out;
    f32x4 x = outv[i];
    bf16x4 m = mm[i];
    x.x += (float)m.x; x.y += (float)m.y; x.z += (float)m.z; x.w += (float)m.w;
    float sum = x.x + x.y + x.z + x.w;
    float sq  = x.x * x.x + x.y * x.y + x.z * x.z + x.w * x.w;
    sum = wave_reduce_sum(sum);
    sq  = wave_reduce_sum(sq);
    __shared__ float ss[4], s2[4];
    if ((t & 63) == 0) { ss[t >> 6] = sum; s2[t >> 6] = sq; }
    __syncthreads();
    sum = ss[0] + ss[1] + ss[2] + ss[3];
    sq  = s2[0] + s2[1] + s2[2] + s2[3];
    float mu  = sum * (1.0f / H);
    float var = sq * (1.0f / H) - mu * mu;
    float inv = rsqrtf(var + EPSF);
    f32x4 g = g2[t], b = b2[t];
    f32x4 o;
    o.x = (x.x - mu) * inv * g.x + b.x;
    o.y = (x.y - mu) * inv * g.y + b.y;
    o.z = (x.z - mu) * inv * g.z + b.z;
    o.w = (x.w - mu) * inv * g.w + b.w;
    outv[i] = o;
}

// ---------------- bf16 MFMA GEMM: C[M,N] = A[M,K] * Bt[N,K]^T + bias ----------------
// 128x128 tile, BK=32, 256 threads (4 waves, each 64x64 via 4x4 of 16x16x32).
// Register-staged, double-buffered LDS pipeline: global->VGPR loads for step
// k+1 issued at top of step k, ds_write at bottom, ONE barrier per step.
// grid.x = M-blocks (so blocks sharing an A-tile land on one XCD: gridDim.x
// = 144, 144%8==0 => XCD = x%8 constant per A row-tile).
template<int N, int K, bool RELU, bool BF16OUT>
__global__ __launch_bounds__(256) void k_gemm(const bf16* __restrict__ A,
                                              const bf16* __restrict__ Bt,
                                              const float* __restrict__ bias,
                                              void* __restrict__ C) {
    __shared__ bf16 sA[2][128 * 32];
    __shared__ bf16 sB[2][128 * 32];
    const int tid  = threadIdx.x;
    const int lane = tid & 63;
    const int wave = tid >> 6;
    const int quad = lane >> 4;
    const int l16  = lane & 15;
    const size_t bm = (size_t)blockIdx.x * 128;   // M-block on x (XCD locality)
    const size_t bn = (size_t)blockIdx.y * 128;
    const int wm = (wave & 1) * 64;
    const int wn = (wave >> 1) * 64;

    f32x4 acc[4][4] = {};

    // Staging: tile = 128 rows x 32 k = 512 granules of 8 bf16 (16 B).
    // Thread t stages granules t and t+256 of both A and B.
    // granule g: row = g>>2, k-off = (g&3)*8; LDS elem offset = g*8 (natural).
    const int r0 = tid >> 2;
    const int q0 = (tid & 3) * 8;
    const bf16* gA0 = A  + (bm + r0)      * (size_t)K + q0;
    const bf16* gA1 = A  + (bm + r0 + 64) * (size_t)K + q0;
    const bf16* gB0 = Bt + (bn + r0)      * (size_t)K + q0;
    const bf16* gB1 = Bt + (bn + r0 + 64) * (size_t)K + q0;

    // prologue: load + stage tile 0
    i32x4 ra0 = *(const i32x4*)(gA0);
    i32x4 ra1 = *(const i32x4*)(gA1);
    i32x4 rb0 = *(const i32x4*)(gB0);
    i32x4 rb1 = *(const i32x4*)(gB1);
    int buf = 0;
    *(i32x4*)(&sA[0][tid * 8])        = ra0;
    *(i32x4*)(&sA[0][tid * 8 + 2048]) = ra1;
    *(i32x4*)(&sB[0][tid * 8])        = rb0;
    *(i32x4*)(&sB[0][tid * 8 + 2048]) = rb1;
    __syncthreads();

    for (int k0 = 0; k0 < K; k0 += 32) {
        const bool has_next = (k0 + 32) < K;
        if (has_next) {   // issue next-tile loads EARLY; consumed only by ds_write below
            ra0 = *(const i32x4*)(gA0 + k0 + 32);
            ra1 = *(const i32x4*)(gA1 + k0 + 32);
            rb0 = *(const i32x4*)(gB0 + k0 + 32);
            rb1 = *(const i32x4*)(gB1 + k0 + 32);
        }

        const bf16* pA = sA[buf];
        const bf16* pB = sB[buf];
        bf16x8 af[4], bfr[4];
        #pragma unroll
        for (int mi = 0; mi < 4; ++mi)
            af[mi] = *(const bf16x8*)(pA + (wm + mi * 16 + l16) * 32 + quad * 8);
        #pragma unroll
        for (int ni = 0; ni < 4; ++ni)
            bfr[ni] = *(const bf16x8*)(pB + (wn + ni * 16 + l16) * 32 + quad * 8);
        #pragma unroll
        for (int mi = 0; mi < 4; ++mi)
            #pragma unroll
            for (int ni = 0; ni < 4; ++ni)
                acc[mi][ni] = __builtin_amdgcn_mfma_f32_16x16x32_bf16(
                    af[mi], bfr[ni], acc[mi][ni], 0, 0, 0);

        if (has_next) {
            buf ^= 1;
            *(i32x4*)(&sA[buf][tid * 8])        = ra0;
            *(i32x4*)(&sA[buf][tid * 8 + 2048]) = ra1;
            *(i32x4*)(&sB[buf][tid * 8])        = rb0;
            *(i32x4*)(&sB[buf][tid * 8 + 2048]) = rb1;
        }
        __syncthreads();   // single barrier per K-step
    }

    // epilogue: D row = quad*4+reg, col = l16 within each 16x16 tile
    #pragma unroll
    for (int mi = 0; mi < 4; ++mi) {
        #pragma unroll
        for (int reg = 0; reg < 4; ++reg) {
            size_t row = bm + wm + mi * 16 + quad * 4 + reg;
            #pragma unroll
            for (int ni = 0; ni < 4; ++ni) {
                int col = wn + ni * 16 + l16;
                float val = acc[mi][ni][reg] + bias[bn + col];
                if (RELU) val = fmaxf(val, 0.f);
                if (BF16OUT) ((bf16*)C)[row * N + bn + col] = (bf16)val;
                else         ((float*)C)[row * N + bn + col] = val;
            }
        }
    }
}

extern "C" void kernel_launch(void* const* d_in, const int* in_sizes, int n_in,
                              void* d_out, int out_size, void* d_ws, size_t ws_size,
                              hipStream_t stream) {
    (void)in_sizes; (void)n_in; (void)out_size; (void)ws_size;
    const float* v   = (const float*)d_in[0];
    const float* q   = (const float*)d_in[1];
    const float* att = (const float*)d_in[2];
    const float* ru  = (const float*)d_in[3];
    const float* g1  = (const float*)d_in[4];
    const float* b1  = (const float*)d_in[5];
    const float* g2  = (const float*)d_in[6];
    const float* b2  = (const float*)d_in[7];
    const float* W1  = (const float*)d_in[8];
    const float* c1  = (const float*)d_in[9];
    const float* W2  = (const float*)d_in[10];
    const float* c2  = (const float*)d_in[11];

    float* out    = (float*)d_out;
    float* ru_out = out + (size_t)M_ROWS * H;

    char* ws = (char*)d_ws;
    float* rusum = (float*)ws;
    float* w     = (float*)(ws + 256);
    size_t off = 256 + (size_t)M_ROWS * sizeof(float);
    off = (off + 255) & ~(size_t)255;
    bf16* mm  = (bf16*)(ws + off); off += (size_t)M_ROWS * H * 2;
    bf16* W1t = (bf16*)(ws + off); off += (size_t)H * MID * 2;
    bf16* W2t = (bf16*)(ws + off); off += (size_t)H * MID * 2;
    bf16* h   = (bf16*)(ws + off); off += (size_t)M_ROWS * MID * 2;

    hipMemsetAsync(rusum, 0, sizeof(float), stream);
    k_rusum<<<M_ROWS / 256, 256, 0, stream>>>(ru, rusum);
    k_gate<<<BS, 64, 0, stream>>>(att, ru, rusum, w, ru_out);
    k_transpose_bf16<<<dim3(MID / 32, H / 32), dim3(32, 8), 0, stream>>>(W1, W1t, H, MID);
    k_transpose_bf16<<<dim3(H / 32, MID / 32), dim3(32, 8), 0, stream>>>(W2, W2t, MID, H);
    k_ln1<<<M_ROWS, 256, 0, stream>>>((const f32x4*)v, (const f32x4*)q,
                                      (const f32x4*)g1, (const f32x4*)b1, w, (bf16x4*)mm);
    k_gemm<MID, H, true, true><<<dim3(M_ROWS / 128, MID / 128), 256, 0, stream>>>(mm, W1t, c1, h);
    k_gemm<H, MID, false, false><<<dim3(M_ROWS / 128, H / 128), 256, 0, stream>>>(h, W2t, c2, out);
    k_ln2<<<M_ROWS, 256, 0, stream>>>(out, (const bf16x4*)mm, (const f32x4*)g2, (const f32x4*)b2);
}

// Round 3
// 524.807 us; speedup vs baseline: 1.3421x; 1.3421x over previous
//
#include <hip/hip_runtime.h>

#define BS 512
#define SRC 36
#define H 1024
#define MID 4096
#define M_ROWS (BS * SRC)   // 18432
#define ALPHAF 8.0f
#define GAMMAF 0.98f
#define EPSF 1e-6f

typedef __bf16 bf16;
typedef __attribute__((ext_vector_type(4))) __bf16 bf16x4;
typedef __attribute__((ext_vector_type(4))) float f32x4;
typedef __attribute__((ext_vector_type(4))) int i32x4;

__device__ __forceinline__ float wave_reduce_sum(float v) {
    #pragma unroll
    for (int off = 32; off > 0; off >>= 1) v += __shfl_xor(v, off, 64);
    return v;
}

__device__ __forceinline__ unsigned char to_fp8(float v) {
    v = fminf(fmaxf(v, -440.f), 440.f);
    int p = __builtin_amdgcn_cvt_pk_fp8_f32(v, 0.f, 0, false);
    return (unsigned char)(p & 0xff);
}

// ---------------- sum(ru) ----------------
__global__ __launch_bounds__(256) void k_rusum(const float* __restrict__ ru,
                                               float* __restrict__ rusum) {
    int i = blockIdx.x * 256 + threadIdx.x;
    float v = ru[i];
    v = wave_reduce_sum(v);
    __shared__ float s[4];
    if ((threadIdx.x & 63) == 0) s[threadIdx.x >> 6] = v;
    __syncthreads();
    if (threadIdx.x == 0) atomicAdd(rusum, s[0] + s[1] + s[2] + s[3]);
}

// ---------------- gate ----------------
__global__ __launch_bounds__(64) void k_gate(const float* __restrict__ att,
                                             const float* __restrict__ ru,
                                             const float* __restrict__ rusum,
                                             float* __restrict__ w,
                                             float* __restrict__ ru_out) {
    int b = blockIdx.x;
    int s = threadIdx.x;
    float rg = 0.f, run = 0.f;
    if (s < SRC) {
        const float* row = att + ((size_t)b * SRC + s) * SRC;
        #pragma unroll
        for (int j = 0; j < SRC; ++j) rg += row[j];
        float scale = (*rusum == 0.0f) ? 1.0f : (1.0f / (1.0f + GAMMAF));
        run = (ru[b * SRC + s] * GAMMAF + rg) * scale;
    }
    float sa = (s < SRC) ? sqrtf(run) : 0.f;
    float S = wave_reduce_sum(sa);
    float T = wave_reduce_sum(run * sa);
    if (s < SRC) {
        float funcF = run * S - T;
        float aw = (funcF > 0.f) ? ALPHAF : (1.0f / ALPHAF);
        ru_out[b * SRC + s] = aw * run;
        w[b * SRC + s] = aw * rg;
    }
}

// ---------------- transpose f32 [rows][cols] -> fp8 [cols][rows] with scale ----------------
__global__ __launch_bounds__(256) void k_transpose_fp8(const float* __restrict__ in,
                                                       unsigned char* __restrict__ out,
                                                       int rows, int cols, float scale) {
    __shared__ float tile[32][33];
    int bx = blockIdx.x * 32, by = blockIdx.y * 32;
    int tx = threadIdx.x;
    #pragma unroll
    for (int j = threadIdx.y; j < 32; j += 8)
        tile[j][tx] = in[(size_t)(by + j) * cols + bx + tx];
    __syncthreads();
    #pragma unroll
    for (int j = threadIdx.y; j < 32; j += 8)
        out[(size_t)(bx + j) * rows + by + tx] = to_fp8(tile[tx][j] * scale);
}

// ---------------- LN1 fused with w-scale -> mm (bf16, for LN2 residual) + mm8 (fp8, /8) ----
__global__ __launch_bounds__(256) void k_ln1(const f32x4* __restrict__ v,
                                             const f32x4* __restrict__ q,
                                             const f32x4* __restrict__ g1,
                                             const f32x4* __restrict__ b1,
                                             const float* __restrict__ w,
                                             bf16x4* __restrict__ mm,
                                             int* __restrict__ mm8) {
    int row = blockIdx.x, t = threadIdx.x;
    size_t i = (size_t)row * 256 + t;
    f32x4 x = v[i];
    f32x4 y = q[i];
    x.x += y.x; x.y += y.y; x.z += y.z; x.w += y.w;
    float sum = x.x + x.y + x.z + x.w;
    float sq  = x.x * x.x + x.y * x.y + x.z * x.z + x.w * x.w;
    sum = wave_reduce_sum(sum);
    sq  = wave_reduce_sum(sq);
    __shared__ float ss[4], s2[4];
    if ((t & 63) == 0) { ss[t >> 6] = sum; s2[t >> 6] = sq; }
    __syncthreads();
    sum = ss[0] + ss[1] + ss[2] + ss[3];
    sq  = s2[0] + s2[1] + s2[2] + s2[3];
    float mu  = sum * (1.0f / H);
    float var = sq * (1.0f / H) - mu * mu;
    float inv = rsqrtf(var + EPSF);
    float ww = w[row];
    f32x4 g = g1[t], b = b1[t];
    float o0 = ww * ((x.x - mu) * inv * g.x + b.x);
    float o1 = ww * ((x.y - mu) * inv * g.y + b.y);
    float o2 = ww * ((x.z - mu) * inv * g.z + b.z);
    float o3 = ww * ((x.w - mu) * inv * g.w + b.w);
    bf16x4 o; o.x = (bf16)o0; o.y = (bf16)o1; o.z = (bf16)o2; o.w = (bf16)o3;
    mm[i] = o;
    // fp8 copy scaled by 1/8 (exact power-of-2)
    float c0 = fminf(fmaxf(o0 * 0.125f, -440.f), 440.f);
    float c1v = fminf(fmaxf(o1 * 0.125f, -440.f), 440.f);
    float c2v = fminf(fmaxf(o2 * 0.125f, -440.f), 440.f);
    float c3 = fminf(fmaxf(o3 * 0.125f, -440.f), 440.f);
    int p = __builtin_amdgcn_cvt_pk_fp8_f32(c0, c1v, 0, false);
    p = __builtin_amdgcn_cvt_pk_fp8_f32(c2v, c3, p, true);
    mm8[i] = p;
}

// ---------------- LN2: out = LN(mm + fc), in place over d_out ----------------
__global__ __launch_bounds__(256) void k_ln2(float* __restrict__ out,
                                             const bf16x4* __restrict__ mm,
                                             const f32x4* __restrict__ g2,
                                             const f32x4* __restrict__ b2) {
    int row = blockIdx.x, t = threadIdx.x;
    size_t i = (size_t)row * 256 + t;
    f32x4* outv = (f32x4*)out;
    f32x4 x = outv[i];
    bf16x4 m = mm[i];
    x.x += (float)m.x; x.y += (float)m.y; x.z += (float)m.z; x.w += (float)m.w;
    float sum = x.x + x.y + x.z + x.w;
    float sq  = x.x * x.x + x.y * x.y + x.z * x.z + x.w * x.w;
    sum = wave_reduce_sum(sum);
    sq  = wave_reduce_sum(sq);
    __shared__ float ss[4], s2[4];
    if ((t & 63) == 0) { ss[t >> 6] = sum; s2[t >> 6] = sq; }
    __syncthreads();
    sum = ss[0] + ss[1] + ss[2] + ss[3];
    sq  = s2[0] + s2[1] + s2[2] + s2[3];
    float mu  = sum * (1.0f / H);
    float var = sq * (1.0f / H) - mu * mu;
    float inv = rsqrtf(var + EPSF);
    f32x4 g = g2[t], b = b2[t];
    f32x4 o;
    o.x = (x.x - mu) * inv * g.x + b.x;
    o.y = (x.y - mu) * inv * g.y + b.y;
    o.z = (x.z - mu) * inv * g.z + b.z;
    o.w = (x.w - mu) * inv * g.w + b.w;
    outv[i] = o;
}

// ---------------- fp8 MFMA GEMM: C[M,N] = A[M,K]*Bt[N,K]^T + bias ----------------
// 128x128 tile, BK=64, register-staged double-buffered LDS, 1 barrier/step.
// LDS K-stride 80 B => ds_read_b64 frag loads are exactly 2-way bank-aliased (free).
// FP8OUT: writes relu(val)/8 as fp8 e4m3 (for GEMM2's A operand); else f32.
template<int N, int K, bool FP8OUT>
__global__ __launch_bounds__(256, 3) void k_gemm_fp8(const unsigned char* __restrict__ A,
                                                     const unsigned char* __restrict__ Bt,
                                                     const float* __restrict__ bias,
                                                     void* __restrict__ C) {
    constexpr int LDK = 80;   // padded K-stride in bytes (BK=64 data + 16 pad)
    __shared__ unsigned char sA[2][128 * LDK];
    __shared__ unsigned char sB[2][128 * LDK];
    const int tid  = threadIdx.x;
    const int lane = tid & 63;
    const int wave = tid >> 6;
    const int quad = lane >> 4;
    const int l16  = lane & 15;
    const size_t bm = (size_t)blockIdx.x * 128;   // M on x: XCD locality for A
    const size_t bn = (size_t)blockIdx.y * 128;
    const int wm = (wave & 1) * 64;
    const int wn = (wave >> 1) * 64;

    f32x4 acc[4][4] = {};

    // staging: thread t loads 16 B at row r0 (+64) col co of the BK=64 slice
    const int r0 = tid >> 2;
    const int co = (tid & 3) * 16;
    const unsigned char* gA0 = A  + (bm + r0)      * (size_t)K + co;
    const unsigned char* gA1 = A  + (bm + r0 + 64) * (size_t)K + co;
    const unsigned char* gB0 = Bt + (bn + r0)      * (size_t)K + co;
    const unsigned char* gB1 = Bt + (bn + r0 + 64) * (size_t)K + co;

    i32x4 ra0 = *(const i32x4*)(gA0);
    i32x4 ra1 = *(const i32x4*)(gA1);
    i32x4 rb0 = *(const i32x4*)(gB0);
    i32x4 rb1 = *(const i32x4*)(gB1);
    int buf = 0;
    *(i32x4*)(&sA[0][r0 * LDK + co])        = ra0;
    *(i32x4*)(&sA[0][(r0 + 64) * LDK + co]) = ra1;
    *(i32x4*)(&sB[0][r0 * LDK + co])        = rb0;
    *(i32x4*)(&sB[0][(r0 + 64) * LDK + co]) = rb1;
    __syncthreads();

    for (int k0 = 0; k0 < K; k0 += 64) {
        const bool has_next = (k0 + 64) < K;
        if (has_next) {   // prefetch next slice into VGPRs; consumed only at ds_write below
            ra0 = *(const i32x4*)(gA0 + k0 + 64);
            ra1 = *(const i32x4*)(gA1 + k0 + 64);
            rb0 = *(const i32x4*)(gB0 + k0 + 64);
            rb1 = *(const i32x4*)(gB1 + k0 + 64);
        }

        const unsigned char* pA = sA[buf];
        const unsigned char* pB = sB[buf];
        long af[2][4], bfr[2][4];
        #pragma unroll
        for (int c = 0; c < 2; ++c) {
            #pragma unroll
            for (int mi = 0; mi < 4; ++mi)
                af[c][mi] = *(const long*)(pA + (wm + mi * 16 + l16) * LDK + c * 32 + quad * 8);
            #pragma unroll
            for (int ni = 0; ni < 4; ++ni)
                bfr[c][ni] = *(const long*)(pB + (wn + ni * 16 + l16) * LDK + c * 32 + quad * 8);
        }
        #pragma unroll
        for (int c = 0; c < 2; ++c)
            #pragma unroll
            for (int mi = 0; mi < 4; ++mi)
                #pragma unroll
                for (int ni = 0; ni < 4; ++ni)
                    acc[mi][ni] = __builtin_amdgcn_mfma_f32_16x16x32_fp8_fp8(
                        af[c][mi], bfr[c][ni], acc[mi][ni], 0, 0, 0);

        if (has_next) {
            buf ^= 1;
            *(i32x4*)(&sA[buf][r0 * LDK + co])        = ra0;
            *(i32x4*)(&sA[buf][(r0 + 64) * LDK + co]) = ra1;
            *(i32x4*)(&sB[buf][r0 * LDK + co])        = rb0;
            *(i32x4*)(&sB[buf][(r0 + 64) * LDK + co]) = rb1;
        }
        __syncthreads();
    }

    // epilogue: D row = quad*4+reg, col = l16 per 16x16 tile (dtype-independent layout)
    #pragma unroll
    for (int mi = 0; mi < 4; ++mi) {
        #pragma unroll
        for (int reg = 0; reg < 4; ++reg) {
            size_t row = bm + wm + mi * 16 + quad * 4 + reg;
            #pragma unroll
            for (int ni = 0; ni < 4; ++ni) {
                int col = wn + ni * 16 + l16;
                float val = acc[mi][ni][reg] + bias[bn + col];
                if (FP8OUT) {
                    // h stored as relu(h)/8 in fp8 (exact pow2 scale; GEMM2 B is W2*8)
                    ((unsigned char*)C)[row * N + bn + col] = to_fp8(fmaxf(val, 0.f) * 0.125f);
                } else {
                    ((float*)C)[row * N + bn + col] = val;
                }
            }
        }
    }
}

extern "C" void kernel_launch(void* const* d_in, const int* in_sizes, int n_in,
                              void* d_out, int out_size, void* d_ws, size_t ws_size,
                              hipStream_t stream) {
    (void)in_sizes; (void)n_in; (void)out_size; (void)ws_size;
    const float* v   = (const float*)d_in[0];
    const float* q   = (const float*)d_in[1];
    const float* att = (const float*)d_in[2];
    const float* ru  = (const float*)d_in[3];
    const float* g1  = (const float*)d_in[4];
    const float* b1  = (const float*)d_in[5];
    const float* g2  = (const float*)d_in[6];
    const float* b2  = (const float*)d_in[7];
    const float* W1  = (const float*)d_in[8];
    const float* c1  = (const float*)d_in[9];
    const float* W2  = (const float*)d_in[10];
    const float* c2  = (const float*)d_in[11];

    float* out    = (float*)d_out;
    float* ru_out = out + (size_t)M_ROWS * H;

    char* ws = (char*)d_ws;
    float* rusum = (float*)ws;
    float* w     = (float*)(ws + 256);
    size_t off = 256 + (size_t)M_ROWS * sizeof(float);
    off = (off + 255) & ~(size_t)255;
    bf16* mm           = (bf16*)(ws + off);          off += (size_t)M_ROWS * H * 2;
    unsigned char* mm8 = (unsigned char*)(ws + off); off += (size_t)M_ROWS * H;
    unsigned char* W1t = (unsigned char*)(ws + off); off += (size_t)H * MID;
    unsigned char* W2t = (unsigned char*)(ws + off); off += (size_t)H * MID;
    unsigned char* h8  = (unsigned char*)(ws + off); off += (size_t)M_ROWS * MID;

    hipMemsetAsync(rusum, 0, sizeof(float), stream);
    k_rusum<<<M_ROWS / 256, 256, 0, stream>>>(ru, rusum);
    k_gate<<<BS, 64, 0, stream>>>(att, ru, rusum, w, ru_out);
    // weights scaled by 8 into fp8 (A operands carry the matching 1/8)
    k_transpose_fp8<<<dim3(MID / 32, H / 32), dim3(32, 8), 0, stream>>>(W1, W1t, H, MID, 8.0f);
    k_transpose_fp8<<<dim3(H / 32, MID / 32), dim3(32, 8), 0, stream>>>(W2, W2t, MID, H, 8.0f);
    k_ln1<<<M_ROWS, 256, 0, stream>>>((const f32x4*)v, (const f32x4*)q,
                                      (const f32x4*)g1, (const f32x4*)b1, w,
                                      (bf16x4*)mm, (int*)mm8);
    k_gemm_fp8<MID, H, true><<<dim3(M_ROWS / 128, MID / 128), 256, 0, stream>>>(mm8, W1t, c1, h8);
    k_gemm_fp8<H, MID, false><<<dim3(M_ROWS / 128, H / 128), 256, 0, stream>>>(h8, W2t, c2, out);
    k_ln2<<<M_ROWS, 256, 0, stream>>>(out, (const bf16x4*)mm, (const f32x4*)g2, (const f32x4*)b2);
}

// Round 4
// 518.809 us; speedup vs baseline: 1.3576x; 1.0116x over previous
//
#include <hip/hip_runtime.h>

#define BS 512
#define SRC 36
#define H 1024
#define MID 4096
#define M_ROWS (BS * SRC)   // 18432
#define ALPHAF 8.0f
#define GAMMAF 0.98f
#define EPSF 1e-6f

typedef __bf16 bf16;
typedef __attribute__((ext_vector_type(4))) __bf16 bf16x4;
typedef __attribute__((ext_vector_type(4))) float f32x4;
typedef __attribute__((ext_vector_type(4))) int i32x4;
typedef __attribute__((ext_vector_type(2))) long i64x2;

__device__ __forceinline__ float wave_reduce_sum(float v) {
    #pragma unroll
    for (int off = 32; off > 0; off >>= 1) v += __shfl_xor(v, off, 64);
    return v;
}

__device__ __forceinline__ unsigned char to_fp8(float v) {
    v = fminf(fmaxf(v, -440.f), 440.f);
    int p = __builtin_amdgcn_cvt_pk_fp8_f32(v, 0.f, 0, false);
    return (unsigned char)(p & 0xff);
}

// ---------------- sum(ru) ----------------
__global__ __launch_bounds__(256) void k_rusum(const float* __restrict__ ru,
                                               float* __restrict__ rusum) {
    int i = blockIdx.x * 256 + threadIdx.x;
    float v = ru[i];
    v = wave_reduce_sum(v);
    __shared__ float s[4];
    if ((threadIdx.x & 63) == 0) s[threadIdx.x >> 6] = v;
    __syncthreads();
    if (threadIdx.x == 0) atomicAdd(rusum, s[0] + s[1] + s[2] + s[3]);
}

// ---------------- gate: rg, ru_new, focal, ru_out, w  (vectorized row loads) ----------------
__global__ __launch_bounds__(64) void k_gate(const float* __restrict__ att,
                                             const float* __restrict__ ru,
                                             const float* __restrict__ rusum,
                                             float* __restrict__ w,
                                             float* __restrict__ ru_out) {
    int b = blockIdx.x;
    int s = threadIdx.x;
    float rg = 0.f, run = 0.f;
    if (s < SRC) {
        // row = 36 floats = 9 aligned f32x4 (s*144 B, 16B-aligned)
        const f32x4* row = (const f32x4*)(att + ((size_t)b * SRC + s) * SRC);
        f32x4 acc4 = row[0];
        #pragma unroll
        for (int j = 1; j < 9; ++j) {
            f32x4 t = row[j];
            acc4.x += t.x; acc4.y += t.y; acc4.z += t.z; acc4.w += t.w;
        }
        rg = acc4.x + acc4.y + acc4.z + acc4.w;
        float scale = (*rusum == 0.0f) ? 1.0f : (1.0f / (1.0f + GAMMAF));
        run = (ru[b * SRC + s] * GAMMAF + rg) * scale;
    }
    float sa = (s < SRC) ? sqrtf(run) : 0.f;
    float S = wave_reduce_sum(sa);
    float T = wave_reduce_sum(run * sa);
    if (s < SRC) {
        float funcF = run * S - T;
        float aw = (funcF > 0.f) ? ALPHAF : (1.0f / ALPHAF);
        ru_out[b * SRC + s] = aw * run;
        w[b * SRC + s] = aw * rg;
    }
}

// ---------------- transpose f32 [rows][cols] -> fp8 [cols][rows] with scale ----------------
__global__ __launch_bounds__(256) void k_transpose_fp8(const float* __restrict__ in,
                                                       unsigned char* __restrict__ out,
                                                       int rows, int cols, float scale) {
    __shared__ float tile[32][33];
    int bx = blockIdx.x * 32, by = blockIdx.y * 32;
    int tx = threadIdx.x;
    #pragma unroll
    for (int j = threadIdx.y; j < 32; j += 8)
        tile[j][tx] = in[(size_t)(by + j) * cols + bx + tx];
    __syncthreads();
    #pragma unroll
    for (int j = threadIdx.y; j < 32; j += 8)
        out[(size_t)(bx + j) * rows + by + tx] = to_fp8(tile[tx][j] * scale);
}

// ---------------- LN1, wave-per-row (no barriers): mm (bf16) + mm8 (fp8 /8) ----------------
__global__ __launch_bounds__(256) void k_ln1(const f32x4* __restrict__ v,
                                             const f32x4* __restrict__ q,
                                             const f32x4* __restrict__ g1,
                                             const f32x4* __restrict__ b1,
                                             const float* __restrict__ w,
                                             bf16x4* __restrict__ mm,
                                             int* __restrict__ mm8) {
    const int lane = threadIdx.x & 63;
    const int row  = blockIdx.x * 4 + (threadIdx.x >> 6);
    const size_t base = (size_t)row * 256;
    f32x4 x[4];
    float sum = 0.f, sq = 0.f;
    #pragma unroll
    for (int p = 0; p < 4; ++p) {
        int g = lane + p * 64;
        f32x4 a = v[base + g];
        f32x4 b = q[base + g];
        a.x += b.x; a.y += b.y; a.z += b.z; a.w += b.w;
        x[p] = a;
        sum += a.x + a.y + a.z + a.w;
        sq  += a.x * a.x + a.y * a.y + a.z * a.z + a.w * a.w;
    }
    sum = wave_reduce_sum(sum);
    sq  = wave_reduce_sum(sq);
    float mu  = sum * (1.0f / H);
    float var = sq * (1.0f / H) - mu * mu;
    float inv = rsqrtf(var + EPSF);
    float ww = w[row];
    #pragma unroll
    for (int p = 0; p < 4; ++p) {
        int g = lane + p * 64;
        f32x4 gg = g1[g], bb = b1[g];
        float o0 = ww * ((x[p].x - mu) * inv * gg.x + bb.x);
        float o1 = ww * ((x[p].y - mu) * inv * gg.y + bb.y);
        float o2 = ww * ((x[p].z - mu) * inv * gg.z + bb.z);
        float o3 = ww * ((x[p].w - mu) * inv * gg.w + bb.w);
        bf16x4 o; o.x = (bf16)o0; o.y = (bf16)o1; o.z = (bf16)o2; o.w = (bf16)o3;
        mm[base + g] = o;
        float c0 = fminf(fmaxf(o0 * 0.125f, -440.f), 440.f);
        float c1 = fminf(fmaxf(o1 * 0.125f, -440.f), 440.f);
        float c2 = fminf(fmaxf(o2 * 0.125f, -440.f), 440.f);
        float c3 = fminf(fmaxf(o3 * 0.125f, -440.f), 440.f);
        int pk = __builtin_amdgcn_cvt_pk_fp8_f32(c0, c1, 0, false);
        pk = __builtin_amdgcn_cvt_pk_fp8_f32(c2, c3, pk, true);
        mm8[base + g] = pk;
    }
}

// ---------------- LN2, wave-per-row: out = LN(mm + fc), fc in bf16 ----------------
__global__ __launch_bounds__(256) void k_ln2(float* __restrict__ out,
                                             const bf16x4* __restrict__ fc,
                                             const bf16x4* __restrict__ mm,
                                             const f32x4* __restrict__ g2,
                                             const f32x4* __restrict__ b2) {
    const int lane = threadIdx.x & 63;
    const int row  = blockIdx.x * 4 + (threadIdx.x >> 6);
    const size_t base = (size_t)row * 256;
    f32x4 x[4];
    float sum = 0.f, sq = 0.f;
    #pragma unroll
    for (int p = 0; p < 4; ++p) {
        int g = lane + p * 64;
        bf16x4 a = fc[base + g];
        bf16x4 b = mm[base + g];
        f32x4 t;
        t.x = (float)a.x + (float)b.x;
        t.y = (float)a.y + (float)b.y;
        t.z = (float)a.z + (float)b.z;
        t.w = (float)a.w + (float)b.w;
        x[p] = t;
        sum += t.x + t.y + t.z + t.w;
        sq  += t.x * t.x + t.y * t.y + t.z * t.z + t.w * t.w;
    }
    sum = wave_reduce_sum(sum);
    sq  = wave_reduce_sum(sq);
    float mu  = sum * (1.0f / H);
    float var = sq * (1.0f / H) - mu * mu;
    float inv = rsqrtf(var + EPSF);
    f32x4* outv = (f32x4*)out;
    #pragma unroll
    for (int p = 0; p < 4; ++p) {
        int g = lane + p * 64;
        f32x4 gg = g2[g], bb = b2[g];
        f32x4 o;
        o.x = (x[p].x - mu) * inv * gg.x + bb.x;
        o.y = (x[p].y - mu) * inv * gg.y + bb.y;
        o.z = (x[p].z - mu) * inv * gg.z + bb.z;
        o.w = (x[p].w - mu) * inv * gg.w + bb.w;
        outv[base + g] = o;
    }
}

// ---------------- fp8 MFMA GEMM: C[M,N] = A[M,K]*Bt[N,K]^T + bias ----------------
// 128x128 tile, BK=64, register-staged double-buffered LDS, 1 barrier/step.
// LDS row layout PERMUTED so each lane's two chunk-fragments are adjacent:
//   row byte p' = quad*16 + c*8 + j   holds global k = c*32 + quad*8 + j
// -> fragment pair is ONE ds_read_b128 (8 reads/wave/step instead of 16 b64).
// OUTMODE: 0 = f32, 1 = bf16, 2 = fp8(relu(x)/8)
template<int N, int K, int OUTMODE>
__global__ __launch_bounds__(256, 3) void k_gemm_fp8(const unsigned char* __restrict__ A,
                                                     const unsigned char* __restrict__ Bt,
                                                     const float* __restrict__ bias,
                                                     void* __restrict__ C) {
    constexpr int LDK = 80;   // padded row stride (64 data + 16)
    __shared__ unsigned char sA[2][128 * LDK];
    __shared__ unsigned char sB[2][128 * LDK];
    const int tid  = threadIdx.x;
    const int lane = tid & 63;
    const int wave = tid >> 6;
    const int quad = lane >> 4;
    const int l16  = lane & 15;
    const size_t bm = (size_t)blockIdx.x * 128;   // M on x: XCD locality for A
    const size_t bn = (size_t)blockIdx.y * 128;
    const int wm = (wave & 1) * 64;
    const int wn = (wave >> 1) * 64;

    f32x4 acc[4][4] = {};

    // staging slots: 128 rows x 4 q-slots; thread t -> rows r0, r0+64 at q
    const int r0 = tid >> 2;
    const int qq = tid & 3;
    const unsigned char* gA0 = A  + (bm + r0)      * (size_t)K + qq * 8;
    const unsigned char* gA1 = A  + (bm + r0 + 64) * (size_t)K + qq * 8;
    const unsigned char* gB0 = Bt + (bn + r0)      * (size_t)K + qq * 8;
    const unsigned char* gB1 = Bt + (bn + r0 + 64) * (size_t)K + qq * 8;
    const int w0 = r0 * LDK + qq * 16;
    const int w1 = (r0 + 64) * LDK + qq * 16;

    unsigned long a00, a01, a10, a11, b00, b01, b10, b11;
    a00 = *(const unsigned long*)(gA0);      a01 = *(const unsigned long*)(gA0 + 32);
    a10 = *(const unsigned long*)(gA1);      a11 = *(const unsigned long*)(gA1 + 32);
    b00 = *(const unsigned long*)(gB0);      b01 = *(const unsigned long*)(gB0 + 32);
    b10 = *(const unsigned long*)(gB1);      b11 = *(const unsigned long*)(gB1 + 32);
    int buf = 0;
    { i64x2 t; t.x = (long)a00; t.y = (long)a01; *(i64x2*)(&sA[0][w0]) = t; }
    { i64x2 t; t.x = (long)a10; t.y = (long)a11; *(i64x2*)(&sA[0][w1]) = t; }
    { i64x2 t; t.x = (long)b00; t.y = (long)b01; *(i64x2*)(&sB[0][w0]) = t; }
    { i64x2 t; t.x = (long)b10; t.y = (long)b11; *(i64x2*)(&sB[0][w1]) = t; }
    __syncthreads();

    for (int k0 = 0; k0 < K; k0 += 64) {
        const bool has_next = (k0 + 64) < K;
        if (has_next) {   // prefetch next slice into VGPRs; consumed only at ds_write below
            a00 = *(const unsigned long*)(gA0 + k0 + 64);
            a01 = *(const unsigned long*)(gA0 + k0 + 96);
            a10 = *(const unsigned long*)(gA1 + k0 + 64);
            a11 = *(const unsigned long*)(gA1 + k0 + 96);
            b00 = *(const unsigned long*)(gB0 + k0 + 64);
            b01 = *(const unsigned long*)(gB0 + k0 + 96);
            b10 = *(const unsigned long*)(gB1 + k0 + 64);
            b11 = *(const unsigned long*)(gB1 + k0 + 96);
        }

        const unsigned char* pA = sA[buf];
        const unsigned char* pB = sB[buf];
        i64x2 afp[4], bfp[4];
        #pragma unroll
        for (int mi = 0; mi < 4; ++mi)
            afp[mi] = *(const i64x2*)(pA + (wm + mi * 16 + l16) * LDK + quad * 16);
        #pragma unroll
        for (int ni = 0; ni < 4; ++ni)
            bfp[ni] = *(const i64x2*)(pB + (wn + ni * 16 + l16) * LDK + quad * 16);
        #pragma unroll
        for (int mi = 0; mi < 4; ++mi)
            #pragma unroll
            for (int ni = 0; ni < 4; ++ni)
                acc[mi][ni] = __builtin_amdgcn_mfma_f32_16x16x32_fp8_fp8(
                    afp[mi].x, bfp[ni].x, acc[mi][ni], 0, 0, 0);
        #pragma unroll
        for (int mi = 0; mi < 4; ++mi)
            #pragma unroll
            for (int ni = 0; ni < 4; ++ni)
                acc[mi][ni] = __builtin_amdgcn_mfma_f32_16x16x32_fp8_fp8(
                    afp[mi].y, bfp[ni].y, acc[mi][ni], 0, 0, 0);

        if (has_next) {
            buf ^= 1;
            { i64x2 t; t.x = (long)a00; t.y = (long)a01; *(i64x2*)(&sA[buf][w0]) = t; }
            { i64x2 t; t.x = (long)a10; t.y = (long)a11; *(i64x2*)(&sA[buf][w1]) = t; }
            { i64x2 t; t.x = (long)b00; t.y = (long)b01; *(i64x2*)(&sB[buf][w0]) = t; }
            { i64x2 t; t.x = (long)b10; t.y = (long)b11; *(i64x2*)(&sB[buf][w1]) = t; }
        }
        __syncthreads();
    }

    // epilogue: D row = quad*4+reg, col = l16 per 16x16 tile
    #pragma unroll
    for (int mi = 0; mi < 4; ++mi) {
        #pragma unroll
        for (int reg = 0; reg < 4; ++reg) {
            size_t row = bm + wm + mi * 16 + quad * 4 + reg;
            #pragma unroll
            for (int ni = 0; ni < 4; ++ni) {
                int col = wn + ni * 16 + l16;
                float val = acc[mi][ni][reg] + bias[bn + col];
                if (OUTMODE == 2) {
                    ((unsigned char*)C)[row * N + bn + col] = to_fp8(fmaxf(val, 0.f) * 0.125f);
                } else if (OUTMODE == 1) {
                    ((bf16*)C)[row * N + bn + col] = (bf16)val;
                } else {
                    ((float*)C)[row * N + bn + col] = val;
                }
            }
        }
    }
}

extern "C" void kernel_launch(void* const* d_in, const int* in_sizes, int n_in,
                              void* d_out, int out_size, void* d_ws, size_t ws_size,
                              hipStream_t stream) {
    (void)in_sizes; (void)n_in; (void)out_size; (void)ws_size;
    const float* v   = (const float*)d_in[0];
    const float* q   = (const float*)d_in[1];
    const float* att = (const float*)d_in[2];
    const float* ru  = (const float*)d_in[3];
    const float* g1  = (const float*)d_in[4];
    const float* b1  = (const float*)d_in[5];
    const float* g2  = (const float*)d_in[6];
    const float* b2  = (const float*)d_in[7];
    const float* W1  = (const float*)d_in[8];
    const float* c1  = (const float*)d_in[9];
    const float* W2  = (const float*)d_in[10];
    const float* c2  = (const float*)d_in[11];

    float* out    = (float*)d_out;
    float* ru_out = out + (size_t)M_ROWS * H;

    char* ws = (char*)d_ws;
    float* rusum = (float*)ws;
    float* w     = (float*)(ws + 256);
    size_t off = 256 + (size_t)M_ROWS * sizeof(float);
    off = (off + 255) & ~(size_t)255;
    bf16* mm           = (bf16*)(ws + off);          off += (size_t)M_ROWS * H * 2;
    bf16* fc           = (bf16*)(ws + off);          off += (size_t)M_ROWS * H * 2;
    unsigned char* mm8 = (unsigned char*)(ws + off); off += (size_t)M_ROWS * H;
    unsigned char* W1t = (unsigned char*)(ws + off); off += (size_t)H * MID;
    unsigned char* W2t = (unsigned char*)(ws + off); off += (size_t)H * MID;
    unsigned char* h8  = (unsigned char*)(ws + off); off += (size_t)M_ROWS * MID;

    hipMemsetAsync(rusum, 0, sizeof(float), stream);
    k_rusum<<<M_ROWS / 256, 256, 0, stream>>>(ru, rusum);
    k_gate<<<BS, 64, 0, stream>>>(att, ru, rusum, w, ru_out);
    k_transpose_fp8<<<dim3(MID / 32, H / 32), dim3(32, 8), 0, stream>>>(W1, W1t, H, MID, 8.0f);
    k_transpose_fp8<<<dim3(H / 32, MID / 32), dim3(32, 8), 0, stream>>>(W2, W2t, MID, H, 8.0f);
    k_ln1<<<M_ROWS / 4, 256, 0, stream>>>((const f32x4*)v, (const f32x4*)q,
                                          (const f32x4*)g1, (const f32x4*)b1, w,
                                          (bf16x4*)mm, (int*)mm8);
    k_gemm_fp8<MID, H, 2><<<dim3(M_ROWS / 128, MID / 128), 256, 0, stream>>>(mm8, W1t, c1, h8);
    k_gemm_fp8<H, MID, 1><<<dim3(M_ROWS / 128, H / 128), 256, 0, stream>>>(h8, W2t, c2, fc);
    k_ln2<<<M_ROWS / 4, 256, 0, stream>>>(out, (const bf16x4*)fc, (const bf16x4*)mm,
                                          (const f32x4*)g2, (const f32x4*)b2);
}